// Round 3
// baseline (378.372 us; speedup 1.0000x reference)
//
#include <hip/hip_runtime.h>
#include <cfloat>
#include <climits>

// Problem constants
#define N_ROWS 65536          // 64*1024 flattened rows
#define DIM 256
#define K_CODES 1024
#define N_ELEM 16777216       // N_ROWS*DIM
#define OUT_LOSS_OFF 16777216
#define OUT_IDX_OFF  16777217

#define ROWS_PB 128           // rows per block (argmin)
#define CT 128                // codes per tile
// Ref computes dists in fp32 with +||x||^2 (~256) -> grid ulp ~3.05e-5; flips
// need exact gap <= ~6.5e-5. Pass-1 (bf16-split MFMA) error ~2e-6. Margin
// 1.5e-4 keeps >2x safety. Proven in rounds 3-4 - do not change semantics.
#define EPS_MARGIN 1.5e-4f
#define SHORTLIST_EPS 6e-4f   // covers exact-gap 6.6e-5 + 2*max|x.elo| ~4.2e-4
#define RB 8                  // flagged rows batched per rescore block

// ws layout (bytes)
#define WS_PARTIALS 0         // 1024 double
#define WS_ESQ      8192      // 1024 float
#define WS_IDX      12288     // 65536 int
#define WS_FLAGCNT  274432    // 1 int
#define WS_FLAGLIST 274436    // up to 65536 int -> ends 536580
#define WS_EHI      540672    // 1024*256 u16 = 512 KB (row-major, for argmin)
#define WS_ELO      1064960   // 512 KB
#define WS_EHIT     1589248   // 512 KB q-major transpose (for rescore) -> ends 2113536

typedef unsigned short u16;
typedef __attribute__((ext_vector_type(8))) short bf16x8;
typedef __attribute__((ext_vector_type(4))) float f32x4;

// ---- async global->LDS 16B (wave-uniform LDS base + lane*16) ----
__device__ __forceinline__ void glds16(const u16* g, u16* l) {
    __builtin_amdgcn_global_load_lds(
        (const __attribute__((address_space(1))) unsigned int*)(const void*)g,
        (__attribute__((address_space(3))) unsigned int*)(void*)l,
        16, 0, 0);
}

// ---- exact two-term bf16 split (RN) ----
__device__ __forceinline__ void bsplit(float x, u16& h, u16& l) {
    unsigned u = __float_as_uint(x);
    unsigned hb = (u + 0x7fffu + ((u >> 16) & 1u)) >> 16;
    h = (u16)hb;
    float hf = __uint_as_float(hb << 16);
    float lf = x - hf;                       // exact
    unsigned u2 = __float_as_uint(lf);
    l = (u16)((u2 + 0x7fffu + ((u2 >> 16) & 1u)) >> 16);
}

// ---- numpy fp32 pairwise sum-of-squares over 256 elements (round-3 proven) ----
__device__ __forceinline__ float np_pairwise_sumsq(const float* __restrict__ a) {
    float half[2];
    #pragma unroll
    for (int h = 0; h < 2; ++h) {
        const float* p = a + h * 128;
        float r[8];
        #pragma unroll
        for (int j = 0; j < 8; ++j) r[j] = __fmul_rn(p[j], p[j]);
        for (int i = 8; i < 128; i += 8) {
            #pragma unroll
            for (int j = 0; j < 8; ++j)
                r[j] = __fadd_rn(r[j], __fmul_rn(p[i + j], p[i + j]));
        }
        half[h] = __fadd_rn(__fadd_rn(__fadd_rn(r[0], r[1]), __fadd_rn(r[2], r[3])),
                            __fadd_rn(__fadd_rn(r[4], r[5]), __fadd_rn(r[6], r[7])));
    }
    return __fadd_rn(half[0], half[1]);
}

// ---------------- prep: split x and e into bf16 hi/lo ----------------
__global__ void xsplit_kernel(const float* __restrict__ x, u16* __restrict__ xhi,
                              u16* __restrict__ xlo) {
    int i4 = blockIdx.x * 256 + threadIdx.x;       // 0..4194303
    float4 v = ((const float4*)x)[i4];
    ushort4 h, l;
    bsplit(v.x, h.x, l.x); bsplit(v.y, h.y, l.y);
    bsplit(v.z, h.z, l.z); bsplit(v.w, h.w, l.w);
    ((ushort4*)xhi)[i4] = h;
    ((ushort4*)xlo)[i4] = l;
}

// e split: row-major hi/lo (argmin staging) + q-major hi transpose (rescore).
// ehiT layout: [qid 0..31][code 0..1023][8 u16], qid = 16B-chunk of the dim axis.
__global__ void esplit_kernel(const float* __restrict__ e, u16* __restrict__ ehi,
                              u16* __restrict__ elo, u16* __restrict__ ehiT) {
    int i4 = blockIdx.x * 256 + threadIdx.x;       // 0..65535
    float4 v = ((const float4*)e)[i4];
    ushort4 h, l;
    bsplit(v.x, h.x, l.x); bsplit(v.y, h.y, l.y);
    bsplit(v.z, h.z, l.z); bsplit(v.w, h.w, l.w);
    ((ushort4*)ehi)[i4] = h;
    ((ushort4*)elo)[i4] = l;
    int c = i4 >> 6;
    int f4 = i4 & 63;
    int qid = f4 >> 1;
    ((ushort4*)ehiT)[((size_t)qid * 1024 + c) * 2 + (f4 & 1)] = h;
}

// ---------------- per-code squared norms (numpy-order fp32, round-3 proven) ----
__global__ void esq_kernel(const float* __restrict__ e, float* __restrict__ esq) {
    int c = blockIdx.x * 256 + threadIdx.x;
    if (c < K_CODES) esq[c] = np_pairwise_sumsq(e + c * DIM);
}

// ---------------- Kernel A: split-bf16 MFMA distance + argmin ----------------
// Round-7: depth-1 prefetch pipeline (T3 minimum-2-phase). 8 waves (512 thr) in
// 4x2 over the 128x128 tile (wave = 32 rows x 64 codes, R1-proven compute), but
// the K-loop is flattened to 32 steps of BK=64 with DOUBLE-BUFFERED LDS tiles:
//   per step: issue next chunk's global_load_lds into buf^1, ds_read+MFMA from
//   buf, (epilogue at ct boundary), single __syncthreads() (vmcnt0 drain now
//   overlapped by ~460cyc of MFMA + epilogue VALU), flip.
// Race proof: step s writes buf^1, reads buf; the one barrier/step orders both
// hand-offs. 128KB LDS -> 1 block/CU (8 waves); pipelining replaces the
// occupancy-based hiding of R1. Barriers 72 -> 33 per block.
// LDS tiles [128][64] u16, 16B-blocks XOR-swizzled by row&7; staging layout is
// lane-linear (byte off = i*1024 + lane*16) -> global_load_lds width 16.
__launch_bounds__(512, 2)
__global__ void argmin_kernel(const u16* __restrict__ xhi, const u16* __restrict__ xlo,
                              const u16* __restrict__ ehi, const u16* __restrict__ elo,
                              const float* __restrict__ esq, int* __restrict__ wsIdx,
                              int* __restrict__ flagCnt, int* __restrict__ flagList) {
    __shared__ __align__(16) unsigned char lds[131072];   // 2 x 64KB tile buffers
    __shared__ float esqAll[K_CODES];                     // 4 KB, loaded once
    u16* ldsU = (u16*)lds;

    const int t = threadIdx.x;
    const int w = t >> 6;               // wave 0..7
    const int l = t & 63;
    const int lane15 = l & 15;
    const int quad = l >> 4;            // 0..3
    const int rowBase = blockIdx.x * ROWS_PB;
    const int wr = w >> 1;              // 0..3: 32-row group
    const int wc = w & 1;               // 0..1: 64-code group

    float bv[8], sv[8]; int bi[8];
    #pragma unroll
    for (int i = 0; i < 8; ++i) { bv[i] = FLT_MAX; sv[i] = FLT_MAX; bi[i] = INT_MAX; }

    // staging role: wave pair (arr, arr+4) copies array arr; each wave half a tile
    const int arr = w & 3;
    const int half = w >> 2;            // 0..1
    const u16* src; int gIsX;
    if (arr == 0)      { src = xhi; gIsX = 1; }
    else if (arr == 1) { src = xlo; gIsX = 1; }
    else if (arr == 2) { src = ehi; gIsX = 0; }
    else               { src = elo; gIsX = 0; }
    const int dstOff = arr * 8192;      // u16 units; arrays at 0/16/32/48 KB
    const int sub = l >> 3;             // row-in-group-of-8
    const int jb = l & 7;               // 16B-block slot
    const int sb = jb ^ sub;            // swizzled source block

    // stage step s (s = ct*4 + ch) into buffer buf
    auto stageStep = [&](int s, int buf) {
        const int ch = s & 3;
        const int gRowBase = gIsX ? rowBase : (s >> 2) * CT;
        u16* base = ldsU + buf * 32768 + dstOff + half * 4096;
        #pragma unroll
        for (int i = 0; i < 8; ++i) {
            int r = half * 64 + i * 8 + sub;
            glds16(src + (size_t)(gRowBase + r) * 256 + ch * 64 + sb * 8,
                   base + i * 512);
        }
    };

    // prologue: esq table + first chunk
    esqAll[t] = esq[t];
    esqAll[t + 512] = esq[t + 512];
    stageStep(0, 0);
    __syncthreads();

    f32x4 acc[2][4];
    int cur = 0;
    for (int s = 0; s < 32; ++s) {
        if ((s & 3) == 0) {
            #pragma unroll
            for (int ti = 0; ti < 2; ++ti)
                #pragma unroll
                for (int tj = 0; tj < 4; ++tj) acc[ti][tj] = (f32x4){0.f, 0.f, 0.f, 0.f};
        }
        if (s < 31) stageStep(s + 1, cur ^ 1);     // prefetch next chunk

        const u16* xhiC = ldsU + cur * 32768;
        const u16* xloC = xhiC + 8192;
        const u16* ehiC = xhiC + 16384;
        const u16* eloC = xhiC + 24576;

        #pragma unroll
        for (int kk = 0; kk < 2; ++kk) {           // two 32-wide k-steps
            bf16x8 ah[2], al4[2], bh[4], bl[4];
            const int blk = kk * 4 + quad;         // 16B-block index in row
            #pragma unroll
            for (int ti = 0; ti < 2; ++ti) {
                int r = wr * 32 + ti * 16 + lane15;
                int off = r * 64 + ((blk ^ (r & 7)) * 8);
                ah[ti]  = *(const bf16x8*)(xhiC + off);
                al4[ti] = *(const bf16x8*)(xloC + off);
            }
            #pragma unroll
            for (int tj = 0; tj < 4; ++tj) {
                int r = wc * 64 + tj * 16 + lane15;
                int off = r * 64 + ((blk ^ (r & 7)) * 8);
                bh[tj] = *(const bf16x8*)(ehiC + off);
                bl[tj] = *(const bf16x8*)(eloC + off);
            }
            #pragma unroll
            for (int ti = 0; ti < 2; ++ti)
                #pragma unroll
                for (int tj = 0; tj < 4; ++tj) {
                    acc[ti][tj] = __builtin_amdgcn_mfma_f32_16x16x32_bf16(al4[ti], bh[tj], acc[ti][tj], 0, 0, 0);
                    acc[ti][tj] = __builtin_amdgcn_mfma_f32_16x16x32_bf16(ah[ti], bl[tj], acc[ti][tj], 0, 0, 0);
                    acc[ti][tj] = __builtin_amdgcn_mfma_f32_16x16x32_bf16(ah[ti], bh[tj], acc[ti][tj], 0, 0, 0);
                }
        }

        if ((s & 3) == 3) {
            // epilogue for ct = s>>2 (register-only; runs inside the drain window)
            // s = ||e||^2 - 2*dot. D-layout: row(M)=quad*4+reg, col(N)=lane&15.
            const int ctBase = (s >> 2) * CT;
            #pragma unroll
            for (int tj = 0; tj < 4; ++tj) {
                int cLoc = wc * 64 + tj * 16 + lane15;
                int c = ctBase + cLoc;
                float cs = esqAll[c];
                #pragma unroll
                for (int ti = 0; ti < 2; ++ti)
                    #pragma unroll
                    for (int r4 = 0; r4 < 4; ++r4) {
                        int slot = ti * 4 + r4;
                        float sc = fmaf(-2.0f, acc[ti][tj][r4], cs);
                        if (sc < bv[slot]) {       // candidates ascend in c
                            sv[slot] = bv[slot]; bv[slot] = sc; bi[slot] = c;
                        } else if (sc < sv[slot]) {
                            sv[slot] = sc;
                        }
                    }
            }
        }
        __syncthreads();                            // drain (overlapped) + handoff
        cur ^= 1;
    }

    // ---- final cross-contributor top-2 merge via LDS (reuses tile memory) ----
    // stride 33 floats: bank = (row+k)%32 -> conflict-free (round-6 proven).
    float* bvA = (float*)lds;                     // [128 rows][33]
    float* svA = (float*)(lds + 16896);
    int*   biA = (int*)(lds + 33792);
    const int contrib = wc * 16 + lane15;         // 0..31
    #pragma unroll
    for (int slot = 0; slot < 8; ++slot) {
        int m = wr * 32 + (slot >> 2) * 16 + quad * 4 + (slot & 3);
        bvA[m * 33 + contrib] = bv[slot];
        svA[m * 33 + contrib] = sv[slot];
        biA[m * 33 + contrib] = bi[slot];
    }
    __syncthreads();

    if (t < ROWS_PB) {
        float bb = FLT_MAX, ss = FLT_MAX;
        int ii = INT_MAX;
        for (int k = 0; k < 32; ++k) {
            float v  = bvA[t * 33 + k];
            int   id = biA[t * 33 + k];
            float s2 = svA[t * 33 + k];
            if (v < bb || (v == bb && id < ii)) {
                ss = fminf(bb, s2);
                bb = v; ii = id;
            } else {
                ss = fminf(ss, v);
            }
        }
        int row = rowBase + t;
        wsIdx[row] = ii;
        if (ss - bb < EPS_MARGIN) {
            int p = atomicAdd(flagCnt, 1);
            flagList[p] = row;
        }
    }
}

// ------- Kernel A2: flagged-row rescore, RB rows batched per block -------
// Phase A: bf16-hi fp32 scores over all 1024 codes via q-major ehiT
// (coalesced; each ehi byte read once per 8 rows) -> per-row shortlist within
// SHORTLIST_EPS of min. Phase B: numpy-emulated quantized score (round-3/4
// proven formula) on shortlist; lexicographic (s, idx) argmin.
__launch_bounds__(256)
__global__ void rescore_kernel(const float* __restrict__ x, const float* __restrict__ e,
                               const u16* __restrict__ ehiT, const float* __restrict__ esq,
                               int* __restrict__ wsIdx, const int* __restrict__ flagCnt,
                               const int* __restrict__ flagList) {
    __shared__ __align__(16) float xsh[RB][DIM];      // 8 KB
    __shared__ float Ash[RB];
    __shared__ float minsh[RB][256];                  // 8 KB
    __shared__ float thrsh[RB];
    __shared__ int scnt[RB];
    __shared__ int slist[RB][32];
    __shared__ float sres[RB][32];
    const int t = threadIdx.x;
    const int cnt = *flagCnt;
    const int ngroups = (cnt + RB - 1) / RB;
    for (int g = blockIdx.x; g < ngroups; g += gridDim.x) {
        const int base = g * RB;
        const int nr = (cnt - base < RB) ? (cnt - base) : RB;
        __syncthreads();                               // protect reuse across groups
        #pragma unroll
        for (int r = 0; r < RB; ++r)
            xsh[r][t] = (r < nr) ? x[(size_t)flagList[base + r] * DIM + t] : 0.0f;
        if (t < RB) scnt[t] = 0;
        __syncthreads();
        if (t < RB) Ash[t] = np_pairwise_sumsq(xsh[t]);

        // phase A: sA[j][r] = dot(x_r, ehi_c), c = j*256+t
        float sA[4][RB];
        #pragma unroll
        for (int j = 0; j < 4; ++j)
            #pragma unroll
            for (int r = 0; r < RB; ++r) sA[j][r] = 0.0f;

        const uint4* eT4 = (const uint4*)ehiT;
        for (int q = 0; q < 32; ++q) {
            float4 xq[RB][2];
            #pragma unroll
            for (int r = 0; r < RB; ++r) {             // broadcast LDS reads
                xq[r][0] = ((const float4*)xsh[r])[2 * q];
                xq[r][1] = ((const float4*)xsh[r])[2 * q + 1];
            }
            #pragma unroll
            for (int j = 0; j < 4; ++j) {
                uint4 uv = eT4[(size_t)q * 1024 + j * 256 + t];   // coalesced
                float e0 = __uint_as_float(uv.x << 16);
                float e1 = __uint_as_float(uv.x & 0xffff0000u);
                float e2 = __uint_as_float(uv.y << 16);
                float e3 = __uint_as_float(uv.y & 0xffff0000u);
                float e4v = __uint_as_float(uv.z << 16);
                float e5 = __uint_as_float(uv.z & 0xffff0000u);
                float e6 = __uint_as_float(uv.w << 16);
                float e7 = __uint_as_float(uv.w & 0xffff0000u);
                #pragma unroll
                for (int r = 0; r < RB; ++r) {
                    float d0 = sA[j][r];
                    d0 = fmaf(e0, xq[r][0].x, d0);
                    d0 = fmaf(e1, xq[r][0].y, d0);
                    d0 = fmaf(e2, xq[r][0].z, d0);
                    d0 = fmaf(e3, xq[r][0].w, d0);
                    d0 = fmaf(e4v, xq[r][1].x, d0);
                    d0 = fmaf(e5, xq[r][1].y, d0);
                    d0 = fmaf(e6, xq[r][1].z, d0);
                    d0 = fmaf(e7, xq[r][1].w, d0);
                    sA[j][r] = d0;
                }
            }
        }
        #pragma unroll
        for (int j = 0; j < 4; ++j) {
            float cs = esq[j * 256 + t];
            #pragma unroll
            for (int r = 0; r < RB; ++r)
                sA[j][r] = fmaf(-2.0f, sA[j][r], cs);
        }
        // per-row parallel min reduction
        #pragma unroll
        for (int r = 0; r < RB; ++r)
            minsh[r][t] = fminf(fminf(sA[0][r], sA[1][r]), fminf(sA[2][r], sA[3][r]));
        __syncthreads();
        for (int off = 128; off > 0; off >>= 1) {
            if (t < off) {
                #pragma unroll
                for (int r = 0; r < RB; ++r)
                    minsh[r][t] = fminf(minsh[r][t], minsh[r][t + off]);
            }
            __syncthreads();
        }
        if (t < RB) thrsh[t] = minsh[t][0] + SHORTLIST_EPS;
        __syncthreads();
        // shortlist build
        #pragma unroll
        for (int j = 0; j < 4; ++j)
            #pragma unroll
            for (int r = 0; r < RB; ++r)
                if (r < nr && sA[j][r] <= thrsh[r]) {
                    int p = atomicAdd(&scnt[r], 1);
                    if (p < 32) slist[r][p] = j * 256 + t;
                }
        __syncthreads();
        // phase B: thread -> (row r = t>>5, shortlist slot k = t&31)
        {
            int r = t >> 5, k = t & 31;
            int ns = scnt[r] < 32 ? scnt[r] : 32;
            if (r < nr && k < ns) {
                int c = slist[r][k];
                const float4* ec4 = (const float4*)(e + (size_t)c * DIM);
                const float4* xc4 = (const float4*)xsh[r];
                double dot = 0.0;
                #pragma unroll 8
                for (int d4 = 0; d4 < 64; ++d4) {
                    float4 ev = ec4[d4];
                    float4 xv = xc4[d4];
                    dot += (double)ev.x * (double)xv.x + (double)ev.y * (double)xv.y
                         + (double)ev.z * (double)xv.z + (double)ev.w * (double)xv.w;
                }
                float M = (float)dot;
                sres[r][k] = __fsub_rn(__fadd_rn(Ash[r], esq[c]), __fmul_rn(2.0f, M));
            }
        }
        __syncthreads();
        if (t < nr) {
            int ns = scnt[t] < 32 ? scnt[t] : 32;
            float bb = FLT_MAX; int ii = INT_MAX;
            for (int k = 0; k < ns; ++k) {
                float s = sres[t][k]; int c = slist[t][k];
                if (s < bb || (s == bb && c < ii)) { bb = s; ii = c; }
            }
            wsIdx[flagList[base + t]] = ii;
        }
    }
}

// ---------------- Kernel B: gather quantized + SSE partials + indices-as-float ----------------
__global__ void gather_kernel(const float* __restrict__ x, const float* __restrict__ e,
                              const int* __restrict__ wsIdx, float* __restrict__ out,
                              double* __restrict__ partials) {
    const float4* x4 = (const float4*)x;
    const float4* e4 = (const float4*)e;
    float4* q4 = (float4*)out;
    float* outIdx = out + OUT_IDX_OFF;
    const int tid = blockIdx.x * 256 + threadIdx.x;   // 0..262143
    double sse = 0.0;
    #pragma unroll 4
    for (int i = 0; i < 16; ++i) {
        int u = tid + i * 262144;      // float4 unit, 0..4194303
        int row = u >> 6;
        int c4 = u & 63;
        int idx = wsIdx[row];
        float4 q = e4[idx * 64 + c4];
        float4 xv = x4[u];
        q4[u] = q;
        double dx = (double)q.x - (double)xv.x;
        double dy = (double)q.y - (double)xv.y;
        double dz = (double)q.z - (double)xv.z;
        double dw = (double)q.w - (double)xv.w;
        sse += dx * dx + dy * dy + dz * dz + dw * dw;
    }
    if (tid < N_ROWS) outIdx[tid] = (float)wsIdx[tid];
    #pragma unroll
    for (int m = 1; m < 64; m <<= 1) sse += __shfl_xor(sse, m);
    __shared__ double wsum[4];
    if ((threadIdx.x & 63) == 0) wsum[threadIdx.x >> 6] = sse;
    __syncthreads();
    if (threadIdx.x == 0)
        partials[blockIdx.x] = wsum[0] + wsum[1] + wsum[2] + wsum[3];
}

// ---------------- Kernel C: final loss reduce ----------------
__global__ void loss_kernel(const double* __restrict__ partials, float* __restrict__ out) {
    __shared__ double sh[256];
    const int t = threadIdx.x;
    double s = partials[t] + partials[t + 256] + partials[t + 512] + partials[t + 768];
    sh[t] = s;
    __syncthreads();
    for (int off = 128; off > 0; off >>= 1) {
        if (t < off) sh[t] += sh[t + off];
        __syncthreads();
    }
    if (t == 0) out[OUT_LOSS_OFF] = (float)(0.25 * sh[0] / (double)N_ELEM);
}

extern "C" void kernel_launch(void* const* d_in, const int* in_sizes, int n_in,
                              void* d_out, int out_size, void* d_ws, size_t ws_size,
                              hipStream_t stream) {
    (void)in_sizes; (void)n_in; (void)out_size; (void)ws_size;
    const float* x = (const float*)d_in[0];
    const float* e = (const float*)d_in[1];
    float* out = (float*)d_out;
    char* ws = (char*)d_ws;
    double* partials = (double*)(ws + WS_PARTIALS);
    float* esq = (float*)(ws + WS_ESQ);
    int* wsIdx = (int*)(ws + WS_IDX);
    int* flagCnt = (int*)(ws + WS_FLAGCNT);
    int* flagList = (int*)(ws + WS_FLAGLIST);
    u16* ehi = (u16*)(ws + WS_EHI);
    u16* elo = (u16*)(ws + WS_ELO);
    u16* ehiT = (u16*)(ws + WS_EHIT);
    // x hi/lo scratch lives in d_out (67 MB); consumed by argmin/rescore, then
    // overwritten by gather (stream-ordered, safe).
    u16* xhi = (u16*)d_out;
    u16* xlo = xhi + N_ELEM;

    hipMemsetAsync(flagCnt, 0, sizeof(int), stream);
    xsplit_kernel<<<16384, 256, 0, stream>>>(x, xhi, xlo);
    esplit_kernel<<<256, 256, 0, stream>>>(e, ehi, elo, ehiT);
    esq_kernel<<<4, 256, 0, stream>>>(e, esq);
    argmin_kernel<<<N_ROWS / ROWS_PB, 512, 0, stream>>>(xhi, xlo, ehi, elo, esq,
                                                        wsIdx, flagCnt, flagList);
    rescore_kernel<<<512, 256, 0, stream>>>(x, e, ehiT, esq, wsIdx, flagCnt, flagList);
    gather_kernel<<<1024, 256, 0, stream>>>(x, e, wsIdx, out, partials);
    loss_kernel<<<1, 256, 0, stream>>>(partials, out);
}

// Round 4
// 346.423 us; speedup vs baseline: 1.0922x; 1.0922x over previous
//
#include <hip/hip_runtime.h>
#include <cfloat>
#include <climits>

// Problem constants
#define N_ROWS 65536          // 64*1024 flattened rows
#define DIM 256
#define K_CODES 1024
#define N_ELEM 16777216       // N_ROWS*DIM
#define OUT_LOSS_OFF 16777216
#define OUT_IDX_OFF  16777217

#define ROWS_PB 128           // rows per block (argmin)
#define CT 128                // codes per tile
// Ref computes dists in fp32 with +||x||^2 (~256) -> grid ulp ~3.05e-5; flips
// need exact gap <= ~6.5e-5. Pass-1 (bf16-split MFMA) error ~2e-6. Margin
// 1.5e-4 keeps >2x safety. Proven in rounds 3-4 - do not change semantics.
#define EPS_MARGIN 1.5e-4f
#define SHORTLIST_EPS 6e-4f   // covers exact-gap 6.6e-5 + 2*max|x.elo| ~4.2e-4
#define RB 8                  // flagged rows batched per rescore block

// ws layout (bytes)
#define WS_PARTIALS 0         // 1024 double
#define WS_ESQ      8192      // 1024 float
#define WS_IDX      12288     // 65536 int
#define WS_FLAGCNT  274432    // 1 int
#define WS_DONECNT  274436    // 1 int (gather last-block counter)
#define WS_FLAGLIST 274440    // up to 65536 int -> ends 536584
#define WS_EHI      540672    // 1024*256 u16 = 512 KB (row-major, for argmin)
#define WS_ELO      1064960   // 512 KB
#define WS_EHIT     1589248   // 512 KB q-major transpose (for rescore) -> ends 2113536

typedef unsigned short u16;
typedef __attribute__((ext_vector_type(8))) short bf16x8;
typedef __attribute__((ext_vector_type(4))) float f32x4;

// ---- async global->LDS 16B (wave-uniform LDS base + lane*16) ----
__device__ __forceinline__ void glds16(const u16* g, u16* l) {
    __builtin_amdgcn_global_load_lds(
        (const __attribute__((address_space(1))) unsigned int*)(const void*)g,
        (__attribute__((address_space(3))) unsigned int*)(void*)l,
        16, 0, 0);
}

// ---- exact two-term bf16 split (RN) ----
__device__ __forceinline__ void bsplit(float x, u16& h, u16& l) {
    unsigned u = __float_as_uint(x);
    unsigned hb = (u + 0x7fffu + ((u >> 16) & 1u)) >> 16;
    h = (u16)hb;
    float hf = __uint_as_float(hb << 16);
    float lf = x - hf;                       // exact
    unsigned u2 = __float_as_uint(lf);
    l = (u16)((u2 + 0x7fffu + ((u2 >> 16) & 1u)) >> 16);
}

// ---- numpy fp32 pairwise sum-of-squares over 256 elements (round-3 proven) ----
__device__ __forceinline__ float np_pairwise_sumsq(const float* __restrict__ a) {
    float half[2];
    #pragma unroll
    for (int h = 0; h < 2; ++h) {
        const float* p = a + h * 128;
        float r[8];
        #pragma unroll
        for (int j = 0; j < 8; ++j) r[j] = __fmul_rn(p[j], p[j]);
        for (int i = 8; i < 128; i += 8) {
            #pragma unroll
            for (int j = 0; j < 8; ++j)
                r[j] = __fadd_rn(r[j], __fmul_rn(p[i + j], p[i + j]));
        }
        half[h] = __fadd_rn(__fadd_rn(__fadd_rn(r[0], r[1]), __fadd_rn(r[2], r[3])),
                            __fadd_rn(__fadd_rn(r[4], r[5]), __fadd_rn(r[6], r[7])));
    }
    return __fadd_rn(half[0], half[1]);
}

// ---------------- fused prep: xsplit + esplit + esq by grid partition ----------------
// blocks [0,16384): x split; [16384,16640): e split (+ehiT); [16640,16644): esq.
// Identical per-element code to the previous three kernels; saves 2 dispatch
// boundaries (round-8: ~100us of wall time is inter-kernel gaps).
__global__ void prep_kernel(const float* __restrict__ x, const float* __restrict__ e,
                            u16* __restrict__ xhi, u16* __restrict__ xlo,
                            u16* __restrict__ ehi, u16* __restrict__ elo,
                            u16* __restrict__ ehiT, float* __restrict__ esqOut) {
    const int b = blockIdx.x;
    if (b < 16384) {
        int i4 = b * 256 + threadIdx.x;            // 0..4194303
        float4 v = ((const float4*)x)[i4];
        ushort4 h, l;
        bsplit(v.x, h.x, l.x); bsplit(v.y, h.y, l.y);
        bsplit(v.z, h.z, l.z); bsplit(v.w, h.w, l.w);
        ((ushort4*)xhi)[i4] = h;
        ((ushort4*)xlo)[i4] = l;
    } else if (b < 16640) {
        int i4 = (b - 16384) * 256 + threadIdx.x;  // 0..65535
        float4 v = ((const float4*)e)[i4];
        ushort4 h, l;
        bsplit(v.x, h.x, l.x); bsplit(v.y, h.y, l.y);
        bsplit(v.z, h.z, l.z); bsplit(v.w, h.w, l.w);
        ((ushort4*)ehi)[i4] = h;
        ((ushort4*)elo)[i4] = l;
        int c = i4 >> 6;
        int f4 = i4 & 63;
        int qid = f4 >> 1;
        ((ushort4*)ehiT)[((size_t)qid * 1024 + c) * 2 + (f4 & 1)] = h;
    } else {
        int c = (b - 16640) * 256 + threadIdx.x;
        if (c < K_CODES) esqOut[c] = np_pairwise_sumsq(e + c * DIM);
    }
}

// ---------------- Kernel A: split-bf16 MFMA distance + argmin ----------------
// R1-proven config (111us): 8 waves (512 thr) in 4x2 over a 128x128 tile
// (wave = 32 rows x 64 codes); 66KB LDS -> 2 blocks/CU = 16 waves/CU; the
// cross-block overlap hides the serial stage->drain latency (round-7/8: dbuf
// at 1 block/CU regressed 111->180us because __syncthreads drains vmcnt(0),
// including just-issued prefetch loads - do not "pipeline" this without
// counted-vmcnt raw barriers).
// LDS tiles [128][64] u16, 16B-blocks XOR-swizzled by row&7; staging layout is
// lane-linear (byte off = i*1024 + lane*16) -> global_load_lds width 16.
__launch_bounds__(512, 4)
__global__ void argmin_kernel(const u16* __restrict__ xhi, const u16* __restrict__ xlo,
                              const u16* __restrict__ ehi, const u16* __restrict__ elo,
                              const float* __restrict__ esq, int* __restrict__ wsIdx,
                              int* __restrict__ flagCnt, int* __restrict__ flagList) {
    __shared__ __align__(16) unsigned char lds[65536];
    __shared__ float esq_s[CT];
    u16* xhiS = (u16*)lds;              // [128][64] swizzled, 16 KB
    u16* xloS = (u16*)(lds + 16384);
    u16* ehiS = (u16*)(lds + 32768);
    u16* eloS = (u16*)(lds + 49152);

    const int t = threadIdx.x;
    const int w = t >> 6;               // wave 0..7
    const int l = t & 63;
    const int lane15 = l & 15;
    const int quad = l >> 4;            // 0..3
    const int rowBase = blockIdx.x * ROWS_PB;
    const int wr = w >> 1;              // 0..3: 32-row group
    const int wc = w & 1;               // 0..1: 64-code group

    float bv[8], sv[8]; int bi[8];
    #pragma unroll
    for (int i = 0; i < 8; ++i) { bv[i] = FLT_MAX; sv[i] = FLT_MAX; bi[i] = INT_MAX; }

    // staging role: wave pair (arr, arr+4) copies array arr; each wave half a tile
    const int arr = w & 3;
    const int half = w >> 2;            // 0..1
    const u16* src; u16* dst; int gIsX;
    if (arr == 0)      { src = xhi; dst = xhiS; gIsX = 1; }
    else if (arr == 1) { src = xlo; dst = xloS; gIsX = 1; }
    else if (arr == 2) { src = ehi; dst = ehiS; gIsX = 0; }
    else               { src = elo; dst = eloS; gIsX = 0; }
    const int sub = l >> 3;             // row-in-group-of-8
    const int jb = l & 7;               // 16B-block slot
    const int sb = jb ^ sub;            // swizzled source block

    for (int ct = 0; ct < 8; ++ct) {
        const int ctBase = ct * CT;
        __syncthreads();                          // prior epilogue/LDS reads done
        if (t < CT) esq_s[t] = esq[ctBase + t];

        f32x4 acc[2][4];
        #pragma unroll
        for (int ti = 0; ti < 2; ++ti)
            #pragma unroll
            for (int tj = 0; tj < 4; ++tj) acc[ti][tj] = (f32x4){0.f, 0.f, 0.f, 0.f};

        for (int ch = 0; ch < 4; ++ch) {
            __syncthreads();
            const int gRowBase = gIsX ? rowBase : ctBase;
            #pragma unroll
            for (int i = 0; i < 8; ++i) {
                int r = half * 64 + i * 8 + sub;
                glds16(src + (size_t)(gRowBase + r) * 256 + ch * 64 + sb * 8,
                       dst + half * 4096 + i * 512);
            }
            __syncthreads();

            #pragma unroll
            for (int kk = 0; kk < 2; ++kk) {      // two 32-wide k-steps
                bf16x8 ah[2], al4[2], bh[4], bl[4];
                const int blk = kk * 4 + quad;    // 16B-block index in row
                #pragma unroll
                for (int ti = 0; ti < 2; ++ti) {
                    int r = wr * 32 + ti * 16 + lane15;
                    int off = r * 64 + ((blk ^ (r & 7)) * 8);
                    ah[ti]  = *(const bf16x8*)(xhiS + off);
                    al4[ti] = *(const bf16x8*)(xloS + off);
                }
                #pragma unroll
                for (int tj = 0; tj < 4; ++tj) {
                    int r = wc * 64 + tj * 16 + lane15;
                    int off = r * 64 + ((blk ^ (r & 7)) * 8);
                    bh[tj] = *(const bf16x8*)(ehiS + off);
                    bl[tj] = *(const bf16x8*)(eloS + off);
                }
                #pragma unroll
                for (int ti = 0; ti < 2; ++ti)
                    #pragma unroll
                    for (int tj = 0; tj < 4; ++tj) {
                        acc[ti][tj] = __builtin_amdgcn_mfma_f32_16x16x32_bf16(al4[ti], bh[tj], acc[ti][tj], 0, 0, 0);
                        acc[ti][tj] = __builtin_amdgcn_mfma_f32_16x16x32_bf16(ah[ti], bl[tj], acc[ti][tj], 0, 0, 0);
                        acc[ti][tj] = __builtin_amdgcn_mfma_f32_16x16x32_bf16(ah[ti], bh[tj], acc[ti][tj], 0, 0, 0);
                    }
            }
        }

        // epilogue: s = ||e||^2 - 2*dot. D-layout: row(M)=quad*4+reg, col(N)=lane&15.
        #pragma unroll
        for (int tj = 0; tj < 4; ++tj) {
            int cLoc = wc * 64 + tj * 16 + lane15;
            float cs = esq_s[cLoc];
            int c = ctBase + cLoc;
            #pragma unroll
            for (int ti = 0; ti < 2; ++ti)
                #pragma unroll
                for (int r4 = 0; r4 < 4; ++r4) {
                    int slot = ti * 4 + r4;
                    float s = fmaf(-2.0f, acc[ti][tj][r4], cs);
                    if (s < bv[slot]) {           // candidates ascend in c
                        sv[slot] = bv[slot]; bv[slot] = s; bi[slot] = c;
                    } else if (s < sv[slot]) {
                        sv[slot] = s;
                    }
                }
        }
    }

    // ---- final cross-contributor top-2 merge via LDS (reuses tile memory) ----
    // stride 33 floats: bank = (row+k)%32 -> conflict-free (round-6 proven).
    __syncthreads();
    float* bvA = (float*)lds;                     // [128 rows][33]
    float* svA = (float*)(lds + 16896);
    int*   biA = (int*)(lds + 33792);
    const int contrib = wc * 16 + lane15;         // 0..31
    #pragma unroll
    for (int slot = 0; slot < 8; ++slot) {
        int m = wr * 32 + (slot >> 2) * 16 + quad * 4 + (slot & 3);
        bvA[m * 33 + contrib] = bv[slot];
        svA[m * 33 + contrib] = sv[slot];
        biA[m * 33 + contrib] = bi[slot];
    }
    __syncthreads();

    if (t < ROWS_PB) {
        float bb = FLT_MAX, ss = FLT_MAX;
        int ii = INT_MAX;
        for (int k = 0; k < 32; ++k) {
            float v  = bvA[t * 33 + k];
            int   id = biA[t * 33 + k];
            float s2 = svA[t * 33 + k];
            if (v < bb || (v == bb && id < ii)) {
                ss = fminf(bb, s2);
                bb = v; ii = id;
            } else {
                ss = fminf(ss, v);
            }
        }
        int row = rowBase + t;
        wsIdx[row] = ii;
        if (ss - bb < EPS_MARGIN) {
            int p = atomicAdd(flagCnt, 1);
            flagList[p] = row;
        }
    }
}

// ------- Kernel A2: flagged-row rescore, RB rows batched per block -------
// Phase A: bf16-hi fp32 scores over all 1024 codes via q-major ehiT
// (coalesced; each ehi byte read once per 8 rows) -> per-row shortlist within
// SHORTLIST_EPS of min. Phase B: numpy-emulated quantized score (round-3/4
// proven formula) on shortlist; lexicographic (s, idx) argmin.
__launch_bounds__(256)
__global__ void rescore_kernel(const float* __restrict__ x, const float* __restrict__ e,
                               const u16* __restrict__ ehiT, const float* __restrict__ esq,
                               int* __restrict__ wsIdx, const int* __restrict__ flagCnt,
                               const int* __restrict__ flagList) {
    __shared__ __align__(16) float xsh[RB][DIM];      // 8 KB
    __shared__ float Ash[RB];
    __shared__ float minsh[RB][256];                  // 8 KB
    __shared__ float thrsh[RB];
    __shared__ int scnt[RB];
    __shared__ int slist[RB][32];
    __shared__ float sres[RB][32];
    const int t = threadIdx.x;
    const int cnt = *flagCnt;
    const int ngroups = (cnt + RB - 1) / RB;
    for (int g = blockIdx.x; g < ngroups; g += gridDim.x) {
        const int base = g * RB;
        const int nr = (cnt - base < RB) ? (cnt - base) : RB;
        __syncthreads();                               // protect reuse across groups
        #pragma unroll
        for (int r = 0; r < RB; ++r)
            xsh[r][t] = (r < nr) ? x[(size_t)flagList[base + r] * DIM + t] : 0.0f;
        if (t < RB) scnt[t] = 0;
        __syncthreads();
        if (t < RB) Ash[t] = np_pairwise_sumsq(xsh[t]);

        // phase A: sA[j][r] = dot(x_r, ehi_c), c = j*256+t
        float sA[4][RB];
        #pragma unroll
        for (int j = 0; j < 4; ++j)
            #pragma unroll
            for (int r = 0; r < RB; ++r) sA[j][r] = 0.0f;

        const uint4* eT4 = (const uint4*)ehiT;
        for (int q = 0; q < 32; ++q) {
            float4 xq[RB][2];
            #pragma unroll
            for (int r = 0; r < RB; ++r) {             // broadcast LDS reads
                xq[r][0] = ((const float4*)xsh[r])[2 * q];
                xq[r][1] = ((const float4*)xsh[r])[2 * q + 1];
            }
            #pragma unroll
            for (int j = 0; j < 4; ++j) {
                uint4 uv = eT4[(size_t)q * 1024 + j * 256 + t];   // coalesced
                float e0 = __uint_as_float(uv.x << 16);
                float e1 = __uint_as_float(uv.x & 0xffff0000u);
                float e2 = __uint_as_float(uv.y << 16);
                float e3 = __uint_as_float(uv.y & 0xffff0000u);
                float e4v = __uint_as_float(uv.z << 16);
                float e5 = __uint_as_float(uv.z & 0xffff0000u);
                float e6 = __uint_as_float(uv.w << 16);
                float e7 = __uint_as_float(uv.w & 0xffff0000u);
                #pragma unroll
                for (int r = 0; r < RB; ++r) {
                    float d0 = sA[j][r];
                    d0 = fmaf(e0, xq[r][0].x, d0);
                    d0 = fmaf(e1, xq[r][0].y, d0);
                    d0 = fmaf(e2, xq[r][0].z, d0);
                    d0 = fmaf(e3, xq[r][0].w, d0);
                    d0 = fmaf(e4v, xq[r][1].x, d0);
                    d0 = fmaf(e5, xq[r][1].y, d0);
                    d0 = fmaf(e6, xq[r][1].z, d0);
                    d0 = fmaf(e7, xq[r][1].w, d0);
                    sA[j][r] = d0;
                }
            }
        }
        #pragma unroll
        for (int j = 0; j < 4; ++j) {
            float cs = esq[j * 256 + t];
            #pragma unroll
            for (int r = 0; r < RB; ++r)
                sA[j][r] = fmaf(-2.0f, sA[j][r], cs);
        }
        // per-row parallel min reduction
        #pragma unroll
        for (int r = 0; r < RB; ++r)
            minsh[r][t] = fminf(fminf(sA[0][r], sA[1][r]), fminf(sA[2][r], sA[3][r]));
        __syncthreads();
        for (int off = 128; off > 0; off >>= 1) {
            if (t < off) {
                #pragma unroll
                for (int r = 0; r < RB; ++r)
                    minsh[r][t] = fminf(minsh[r][t], minsh[r][t + off]);
            }
            __syncthreads();
        }
        if (t < RB) thrsh[t] = minsh[t][0] + SHORTLIST_EPS;
        __syncthreads();
        // shortlist build
        #pragma unroll
        for (int j = 0; j < 4; ++j)
            #pragma unroll
            for (int r = 0; r < RB; ++r)
                if (r < nr && sA[j][r] <= thrsh[r]) {
                    int p = atomicAdd(&scnt[r], 1);
                    if (p < 32) slist[r][p] = j * 256 + t;
                }
        __syncthreads();
        // phase B: thread -> (row r = t>>5, shortlist slot k = t&31)
        {
            int r = t >> 5, k = t & 31;
            int ns = scnt[r] < 32 ? scnt[r] : 32;
            if (r < nr && k < ns) {
                int c = slist[r][k];
                const float4* ec4 = (const float4*)(e + (size_t)c * DIM);
                const float4* xc4 = (const float4*)xsh[r];
                double dot = 0.0;
                #pragma unroll 8
                for (int d4 = 0; d4 < 64; ++d4) {
                    float4 ev = ec4[d4];
                    float4 xv = xc4[d4];
                    dot += (double)ev.x * (double)xv.x + (double)ev.y * (double)xv.y
                         + (double)ev.z * (double)xv.z + (double)ev.w * (double)xv.w;
                }
                float M = (float)dot;
                sres[r][k] = __fsub_rn(__fadd_rn(Ash[r], esq[c]), __fmul_rn(2.0f, M));
            }
        }
        __syncthreads();
        if (t < nr) {
            int ns = scnt[t] < 32 ? scnt[t] : 32;
            float bb = FLT_MAX; int ii = INT_MAX;
            for (int k = 0; k < ns; ++k) {
                float s = sres[t][k]; int c = slist[t][k];
                if (s < bb || (s == bb && c < ii)) { bb = s; ii = c; }
            }
            wsIdx[flagList[base + t]] = ii;
        }
    }
}

// ---- Kernel B: gather quantized + SSE partials + indices + fused final loss ----
// Last-block-done pattern: writer blocks do {plain partial store, device fence,
// atomicAdd(doneCnt)}; the block observing prev==1023 re-reads all partials via
// __hip_atomic_load(AGENT) (bypasses non-coherent per-XCD L2 - G16) and does
// the SAME fixed-order reduction the old loss_kernel did (bit-identical loss).
__global__ void gather_kernel(const float* __restrict__ x, const float* __restrict__ e,
                              const int* __restrict__ wsIdx, float* __restrict__ out,
                              double* __restrict__ partials, int* __restrict__ doneCnt) {
    const float4* x4 = (const float4*)x;
    const float4* e4 = (const float4*)e;
    float4* q4 = (float4*)out;
    float* outIdx = out + OUT_IDX_OFF;
    const int tid = blockIdx.x * 256 + threadIdx.x;   // 0..262143
    double sse = 0.0;
    #pragma unroll 4
    for (int i = 0; i < 16; ++i) {
        int u = tid + i * 262144;      // float4 unit, 0..4194303
        int row = u >> 6;
        int c4 = u & 63;
        int idx = wsIdx[row];
        float4 q = e4[idx * 64 + c4];
        float4 xv = x4[u];
        q4[u] = q;
        double dx = (double)q.x - (double)xv.x;
        double dy = (double)q.y - (double)xv.y;
        double dz = (double)q.z - (double)xv.z;
        double dw = (double)q.w - (double)xv.w;
        sse += dx * dx + dy * dy + dz * dz + dw * dw;
    }
    if (tid < N_ROWS) outIdx[tid] = (float)wsIdx[tid];
    #pragma unroll
    for (int m = 1; m < 64; m <<= 1) sse += __shfl_xor(sse, m);
    __shared__ double wsum[4];
    __shared__ int lastB;
    if ((threadIdx.x & 63) == 0) wsum[threadIdx.x >> 6] = sse;
    __syncthreads();
    if (threadIdx.x == 0) {
        partials[blockIdx.x] = wsum[0] + wsum[1] + wsum[2] + wsum[3];
        __threadfence();                               // release partial to device
        unsigned prev = atomicAdd((unsigned*)doneCnt, 1u);
        lastB = (prev == (unsigned)(gridDim.x - 1)) ? 1 : 0;
    }
    __syncthreads();
    if (lastB) {
        __shared__ double sh[256];
        const int t = threadIdx.x;
        double s = __hip_atomic_load(&partials[t],       __ATOMIC_RELAXED, __HIP_MEMORY_SCOPE_AGENT)
                 + __hip_atomic_load(&partials[t + 256], __ATOMIC_RELAXED, __HIP_MEMORY_SCOPE_AGENT)
                 + __hip_atomic_load(&partials[t + 512], __ATOMIC_RELAXED, __HIP_MEMORY_SCOPE_AGENT)
                 + __hip_atomic_load(&partials[t + 768], __ATOMIC_RELAXED, __HIP_MEMORY_SCOPE_AGENT);
        sh[t] = s;
        __syncthreads();
        for (int off = 128; off > 0; off >>= 1) {
            if (t < off) sh[t] += sh[t + off];
            __syncthreads();
        }
        if (t == 0) out[OUT_LOSS_OFF] = (float)(0.25 * sh[0] / (double)N_ELEM);
    }
}

extern "C" void kernel_launch(void* const* d_in, const int* in_sizes, int n_in,
                              void* d_out, int out_size, void* d_ws, size_t ws_size,
                              hipStream_t stream) {
    (void)in_sizes; (void)n_in; (void)out_size; (void)ws_size;
    const float* x = (const float*)d_in[0];
    const float* e = (const float*)d_in[1];
    float* out = (float*)d_out;
    char* ws = (char*)d_ws;
    double* partials = (double*)(ws + WS_PARTIALS);
    float* esq = (float*)(ws + WS_ESQ);
    int* wsIdx = (int*)(ws + WS_IDX);
    int* flagCnt = (int*)(ws + WS_FLAGCNT);
    int* doneCnt = (int*)(ws + WS_DONECNT);
    int* flagList = (int*)(ws + WS_FLAGLIST);
    u16* ehi = (u16*)(ws + WS_EHI);
    u16* elo = (u16*)(ws + WS_ELO);
    u16* ehiT = (u16*)(ws + WS_EHIT);
    // x hi/lo scratch lives in d_out (67 MB); consumed by argmin/rescore, then
    // overwritten by gather (stream-ordered, safe).
    u16* xhi = (u16*)d_out;
    u16* xlo = xhi + N_ELEM;

    hipMemsetAsync(flagCnt, 0, 2 * sizeof(int), stream);   // flagCnt + doneCnt
    prep_kernel<<<16644, 256, 0, stream>>>(x, e, xhi, xlo, ehi, elo, ehiT, esq);
    argmin_kernel<<<N_ROWS / ROWS_PB, 512, 0, stream>>>(xhi, xlo, ehi, elo, esq,
                                                        wsIdx, flagCnt, flagList);
    rescore_kernel<<<512, 256, 0, stream>>>(x, e, ehiT, esq, wsIdx, flagCnt, flagList);
    gather_kernel<<<1024, 256, 0, stream>>>(x, e, wsIdx, out, partials, doneCnt);
}

// Round 5
// 313.654 us; speedup vs baseline: 1.2063x; 1.1045x over previous
//
#include <hip/hip_runtime.h>
#include <cfloat>
#include <climits>

// Problem constants
#define N_ROWS 65536          // 64*1024 flattened rows
#define DIM 256
#define K_CODES 1024
#define N_ELEM 16777216       // N_ROWS*DIM
#define OUT_LOSS_OFF 16777216
#define OUT_IDX_OFF  16777217

#define ROWS_PB 128           // rows per block (argmin)
#define CT 128                // codes per tile
// Ref computes dists in fp32 with +||x||^2 (~256) -> grid ulp ~3.05e-5; flips
// need exact gap <= ~6.5e-5. Pass-1 (bf16-split MFMA) error ~2e-6..4e-6. Margin
// 1.5e-4 keeps >18x safety. EPS logic needs only |err| << margin - any
// nearest-rounding split qualifies (R5: split moved in-kernel via cvt_pk RNE).
#define EPS_MARGIN 1.5e-4f
#define SHORTLIST_EPS 6e-4f   // covers exact-gap 6.6e-5 + 2*max|x.elo| ~4.2e-4
#define RB 8                  // flagged rows batched per rescore block

// ws layout (bytes)
#define WS_PARTIALS 0         // 1024 double
#define WS_ESQ      8192      // 1024 float
#define WS_IDX      12288     // 65536 int
#define WS_FLAGCNT  274432    // 1 int
#define WS_FLAGLIST 274436    // up to 65536 int -> ends 536580
#define WS_EHI      540672    // 1024*256 u16 = 512 KB (row-major, for argmin)
#define WS_ELO      1064960   // 512 KB
#define WS_EHIT     1589248   // 512 KB q-major transpose (for rescore) -> ends 2113536

typedef unsigned short u16;
typedef __attribute__((ext_vector_type(8))) short bf16x8;
typedef __attribute__((ext_vector_type(4))) float f32x4;
typedef union { bf16x8 v; unsigned u[4]; } frag_u;

// ---- async global->LDS 16B (wave-uniform LDS base + lane*16) ----
__device__ __forceinline__ void glds16(const void* g, void* l) {
    __builtin_amdgcn_global_load_lds(
        (const __attribute__((address_space(1))) unsigned int*)g,
        (__attribute__((address_space(3))) unsigned int*)l,
        16, 0, 0);
}

// ---- packed f32->bf16 RNE (2 elements/op); pure asm (no side effects) ----
__device__ __forceinline__ unsigned cvt_pk_bf16(float lo, float hi) {
    unsigned r;
    asm("v_cvt_pk_bf16_f32 %0, %1, %2" : "=v"(r) : "v"(lo), "v"(hi));
    return r;
}

// ---- exact two-term bf16 split of 8 f32 -> (hi8, lo8) fragments ----
// hi = RNE-bf16(x); lf = x - hi (exact, Sterbenz); lo = RNE-bf16(lf).
__device__ __forceinline__ void split8(float4 a, float4 b, bf16x8& h8, bf16x8& l8) {
    frag_u H, L;
    float f0 = a.x, f1 = a.y, f2 = a.z, f3 = a.w;
    float f4 = b.x, f5 = b.y, f6 = b.z, f7 = b.w;
    const float* f[8] = {&f0,&f1,&f2,&f3,&f4,&f5,&f6,&f7};
    #pragma unroll
    for (int p = 0; p < 4; ++p) {
        float xl = *f[2*p], xh = *f[2*p+1];
        unsigned hw = cvt_pk_bf16(xl, xh);
        float hfl = __uint_as_float(hw << 16);
        float hfh = __uint_as_float(hw & 0xffff0000u);
        H.u[p] = hw;
        L.u[p] = cvt_pk_bf16(xl - hfl, xh - hfh);
    }
    h8 = H.v; l8 = L.v;
}

// ---- exact two-term bf16 split (RN, scalar bit version - esplit only) ----
__device__ __forceinline__ void bsplit(float x, u16& h, u16& l) {
    unsigned u = __float_as_uint(x);
    unsigned hb = (u + 0x7fffu + ((u >> 16) & 1u)) >> 16;
    h = (u16)hb;
    float hf = __uint_as_float(hb << 16);
    float lf = x - hf;                       // exact
    unsigned u2 = __float_as_uint(lf);
    l = (u16)((u2 + 0x7fffu + ((u2 >> 16) & 1u)) >> 16);
}

// ---- numpy fp32 pairwise sum-of-squares over 256 elements (round-3 proven) ----
__device__ __forceinline__ float np_pairwise_sumsq(const float* __restrict__ a) {
    float half[2];
    #pragma unroll
    for (int h = 0; h < 2; ++h) {
        const float* p = a + h * 128;
        float r[8];
        #pragma unroll
        for (int j = 0; j < 8; ++j) r[j] = __fmul_rn(p[j], p[j]);
        for (int i = 8; i < 128; i += 8) {
            #pragma unroll
            for (int j = 0; j < 8; ++j)
                r[j] = __fadd_rn(r[j], __fmul_rn(p[i + j], p[i + j]));
        }
        half[h] = __fadd_rn(__fadd_rn(__fadd_rn(r[0], r[1]), __fadd_rn(r[2], r[3])),
                            __fadd_rn(__fadd_rn(r[4], r[5]), __fadd_rn(r[6], r[7])));
    }
    return __fadd_rn(half[0], half[1]);
}

// e split: row-major hi/lo (argmin staging) + q-major hi transpose (rescore).
// ehiT layout: [qid 0..31][code 0..1023][8 u16], qid = 16B-chunk of the dim axis.
// (xsplit kernel deleted in R5: x is split on the fly inside argmin.)
__global__ void esplit_kernel(const float* __restrict__ e, u16* __restrict__ ehi,
                              u16* __restrict__ elo, u16* __restrict__ ehiT) {
    int i4 = blockIdx.x * 256 + threadIdx.x;       // 0..65535
    float4 v = ((const float4*)e)[i4];
    ushort4 h, l;
    bsplit(v.x, h.x, l.x); bsplit(v.y, h.y, l.y);
    bsplit(v.z, h.z, l.z); bsplit(v.w, h.w, l.w);
    ((ushort4*)ehi)[i4] = h;
    ((ushort4*)elo)[i4] = l;
    int c = i4 >> 6;
    int f4 = i4 & 63;
    int qid = f4 >> 1;
    ((ushort4*)ehiT)[((size_t)qid * 1024 + c) * 2 + (f4 & 1)] = h;
}

// ---------------- per-code squared norms (numpy-order fp32, round-3 proven) ----
__global__ void esq_kernel(const float* __restrict__ e, float* __restrict__ esq) {
    int c = blockIdx.x * 256 + threadIdx.x;
    if (c < K_CODES) esq[c] = np_pairwise_sumsq(e + c * DIM);
}

// ---------------- Kernel A: split-bf16 MFMA distance + argmin ----------------
// R1-proven schedule (111us): 8 waves (512 thr) in 4x2 over a 128x128 tile
// (wave = 32 rows x 64 codes); 66KB LDS -> 2 blocks/CU = 16 waves/CU; the
// cross-block overlap hides the serial stage->drain latency (R3: dbuf at
// 1 block/CU regressed to 180us - __syncthreads drains vmcnt(0) including
// just-issued prefetch; do not pipeline without counted-vmcnt raw barriers).
// R5: x staged as RAW f32 (32KB/chunk, same total LDS as the old xhi+xlo
// tiles) and split to bf16 hi/lo in-register via v_cvt_pk_bf16_f32 while
// building A-fragments -> the xsplit kernel (128MB of HBM traffic) is gone.
// x LDS tile [128][64] f32; 16B-blocks swizzled slot = jb ^ (row&15)
// -> 16 distinct slots per 16-lane read group = 2-way bank alias (free).
// e LDS tiles [128][64] u16, 16B-blocks XOR-swizzled by row&7 (R1 layout).
__launch_bounds__(512, 4)
__global__ void argmin_kernel(const float* __restrict__ x,
                              const u16* __restrict__ ehi, const u16* __restrict__ elo,
                              const float* __restrict__ esq, int* __restrict__ wsIdx,
                              int* __restrict__ flagCnt, int* __restrict__ flagList) {
    __shared__ __align__(16) unsigned char lds[65536];
    __shared__ float esq_s[CT];
    float* xSf  = (float*)lds;          // [128][64] f32, swizzled, 32 KB
    u16* ehiS = (u16*)(lds + 32768);    // [128][64] u16, swizzled, 16 KB
    u16* eloS = (u16*)(lds + 49152);

    const int t = threadIdx.x;
    const int w = t >> 6;               // wave 0..7
    const int l = t & 63;
    const int lane15 = l & 15;
    const int quad = l >> 4;            // 0..3
    const int rowBase = blockIdx.x * ROWS_PB;
    const int wr = w >> 1;              // 0..3: 32-row group
    const int wc = w & 1;               // 0..1: 64-code group

    float bv[8], sv[8]; int bi[8];
    #pragma unroll
    for (int i = 0; i < 8; ++i) { bv[i] = FLT_MAX; sv[i] = FLT_MAX; bi[i] = INT_MAX; }

    // staging roles: waves 0-3 stage x f32 (32 rows each, 8 loads of 4 rows);
    // waves 4,5 stage ehi halves; waves 6,7 stage elo halves (8 loads of 8 rows).
    const int sub4 = l >> 4;            // x: row-in-group-of-4
    const int jb16 = l & 15;            // x: 16B-block slot in 256B row
    const int sub8 = l >> 3;            // e: row-in-group-of-8
    const int jb8 = l & 7;              // e: 16B-block slot in 128B row
    const int sb8 = jb8 ^ sub8;         // e: swizzled source block
    const u16* srcE = (w < 6) ? ehi : elo;
    u16* dstE = (w < 6) ? ehiS : eloS;
    const int halfE = w & 1;

    for (int ct = 0; ct < 8; ++ct) {
        const int ctBase = ct * CT;
        __syncthreads();                          // prior epilogue/LDS reads done
        if (t < CT) esq_s[t] = esq[ctBase + t];

        f32x4 acc[2][4];
        #pragma unroll
        for (int ti = 0; ti < 2; ++ti)
            #pragma unroll
            for (int tj = 0; tj < 4; ++tj) acc[ti][tj] = (f32x4){0.f, 0.f, 0.f, 0.f};

        for (int ch = 0; ch < 4; ++ch) {
            __syncthreads();
            if (w < 4) {
                #pragma unroll
                for (int i = 0; i < 8; ++i) {
                    int r = w * 32 + i * 4 + sub4;
                    int sbx = jb16 ^ (r & 15);
                    glds16(x + (size_t)(rowBase + r) * 256 + ch * 64 + sbx * 4,
                           (unsigned char*)lds + (w * 8 + i) * 1024);
                }
            } else {
                #pragma unroll
                for (int i = 0; i < 8; ++i) {
                    int r = halfE * 64 + i * 8 + sub8;
                    glds16(srcE + (size_t)(ctBase + r) * 256 + ch * 64 + sb8 * 8,
                           dstE + halfE * 4096 + i * 512);
                }
            }
            __syncthreads();

            #pragma unroll
            for (int kk = 0; kk < 2; ++kk) {      // two 32-wide k-steps
                bf16x8 ah[2], al4[2], bh[4], bl[4];
                const int blk = kk * 4 + quad;    // 16B-block index (of 8) in e-row
                #pragma unroll
                for (int ti = 0; ti < 2; ++ti) {
                    int r = wr * 32 + ti * 16 + lane15;
                    int base = r * 64;
                    int s0 = ((2 * blk) ^ (r & 15)) * 4;
                    int s1 = ((2 * blk + 1) ^ (r & 15)) * 4;
                    float4 va = *(const float4*)(xSf + base + s0);
                    float4 vb = *(const float4*)(xSf + base + s1);
                    split8(va, vb, ah[ti], al4[ti]);
                }
                #pragma unroll
                for (int tj = 0; tj < 4; ++tj) {
                    int r = wc * 64 + tj * 16 + lane15;
                    int off = r * 64 + ((blk ^ (r & 7)) * 8);
                    bh[tj] = *(const bf16x8*)(ehiS + off);
                    bl[tj] = *(const bf16x8*)(eloS + off);
                }
                #pragma unroll
                for (int ti = 0; ti < 2; ++ti)
                    #pragma unroll
                    for (int tj = 0; tj < 4; ++tj) {
                        acc[ti][tj] = __builtin_amdgcn_mfma_f32_16x16x32_bf16(al4[ti], bh[tj], acc[ti][tj], 0, 0, 0);
                        acc[ti][tj] = __builtin_amdgcn_mfma_f32_16x16x32_bf16(ah[ti], bl[tj], acc[ti][tj], 0, 0, 0);
                        acc[ti][tj] = __builtin_amdgcn_mfma_f32_16x16x32_bf16(ah[ti], bh[tj], acc[ti][tj], 0, 0, 0);
                    }
            }
        }

        // epilogue: s = ||e||^2 - 2*dot. D-layout: row(M)=quad*4+reg, col(N)=lane&15.
        #pragma unroll
        for (int tj = 0; tj < 4; ++tj) {
            int cLoc = wc * 64 + tj * 16 + lane15;
            float cs = esq_s[cLoc];
            int c = ctBase + cLoc;
            #pragma unroll
            for (int ti = 0; ti < 2; ++ti)
                #pragma unroll
                for (int r4 = 0; r4 < 4; ++r4) {
                    int slot = ti * 4 + r4;
                    float s = fmaf(-2.0f, acc[ti][tj][r4], cs);
                    if (s < bv[slot]) {           // candidates ascend in c
                        sv[slot] = bv[slot]; bv[slot] = s; bi[slot] = c;
                    } else if (s < sv[slot]) {
                        sv[slot] = s;
                    }
                }
        }
    }

    // ---- final cross-contributor top-2 merge via LDS (reuses tile memory) ----
    // stride 33 floats: bank = (row+k)%32 -> conflict-free (round-6 proven).
    __syncthreads();
    float* bvA = (float*)lds;                     // [128 rows][33]
    float* svA = (float*)(lds + 16896);
    int*   biA = (int*)(lds + 33792);
    const int contrib = wc * 16 + lane15;         // 0..31
    #pragma unroll
    for (int slot = 0; slot < 8; ++slot) {
        int m = wr * 32 + (slot >> 2) * 16 + quad * 4 + (slot & 3);
        bvA[m * 33 + contrib] = bv[slot];
        svA[m * 33 + contrib] = sv[slot];
        biA[m * 33 + contrib] = bi[slot];
    }
    __syncthreads();

    if (t < ROWS_PB) {
        float bb = FLT_MAX, ss = FLT_MAX;
        int ii = INT_MAX;
        for (int k = 0; k < 32; ++k) {
            float v  = bvA[t * 33 + k];
            int   id = biA[t * 33 + k];
            float s2 = svA[t * 33 + k];
            if (v < bb || (v == bb && id < ii)) {
                ss = fminf(bb, s2);
                bb = v; ii = id;
            } else {
                ss = fminf(ss, v);
            }
        }
        int row = rowBase + t;
        wsIdx[row] = ii;
        if (ss - bb < EPS_MARGIN) {
            int p = atomicAdd(flagCnt, 1);
            flagList[p] = row;
        }
    }
}

// ------- Kernel A2: flagged-row rescore, RB rows batched per block -------
// Phase A: bf16-hi fp32 scores over all 1024 codes via q-major ehiT
// (coalesced; each ehi byte read once per 8 rows) -> per-row shortlist within
// SHORTLIST_EPS of min. Phase B: numpy-emulated quantized score (round-3/4
// proven formula) on shortlist; lexicographic (s, idx) argmin.
__launch_bounds__(256)
__global__ void rescore_kernel(const float* __restrict__ x, const float* __restrict__ e,
                               const u16* __restrict__ ehiT, const float* __restrict__ esq,
                               int* __restrict__ wsIdx, const int* __restrict__ flagCnt,
                               const int* __restrict__ flagList) {
    __shared__ __align__(16) float xsh[RB][DIM];      // 8 KB
    __shared__ float Ash[RB];
    __shared__ float minsh[RB][256];                  // 8 KB
    __shared__ float thrsh[RB];
    __shared__ int scnt[RB];
    __shared__ int slist[RB][32];
    __shared__ float sres[RB][32];
    const int t = threadIdx.x;
    const int cnt = *flagCnt;
    const int ngroups = (cnt + RB - 1) / RB;
    for (int g = blockIdx.x; g < ngroups; g += gridDim.x) {
        const int base = g * RB;
        const int nr = (cnt - base < RB) ? (cnt - base) : RB;
        __syncthreads();                               // protect reuse across groups
        #pragma unroll
        for (int r = 0; r < RB; ++r)
            xsh[r][t] = (r < nr) ? x[(size_t)flagList[base + r] * DIM + t] : 0.0f;
        if (t < RB) scnt[t] = 0;
        __syncthreads();
        if (t < RB) Ash[t] = np_pairwise_sumsq(xsh[t]);

        // phase A: sA[j][r] = dot(x_r, ehi_c), c = j*256+t
        float sA[4][RB];
        #pragma unroll
        for (int j = 0; j < 4; ++j)
            #pragma unroll
            for (int r = 0; r < RB; ++r) sA[j][r] = 0.0f;

        const uint4* eT4 = (const uint4*)ehiT;
        for (int q = 0; q < 32; ++q) {
            float4 xq[RB][2];
            #pragma unroll
            for (int r = 0; r < RB; ++r) {             // broadcast LDS reads
                xq[r][0] = ((const float4*)xsh[r])[2 * q];
                xq[r][1] = ((const float4*)xsh[r])[2 * q + 1];
            }
            #pragma unroll
            for (int j = 0; j < 4; ++j) {
                uint4 uv = eT4[(size_t)q * 1024 + j * 256 + t];   // coalesced
                float e0 = __uint_as_float(uv.x << 16);
                float e1 = __uint_as_float(uv.x & 0xffff0000u);
                float e2 = __uint_as_float(uv.y << 16);
                float e3 = __uint_as_float(uv.y & 0xffff0000u);
                float e4v = __uint_as_float(uv.z << 16);
                float e5 = __uint_as_float(uv.z & 0xffff0000u);
                float e6 = __uint_as_float(uv.w << 16);
                float e7 = __uint_as_float(uv.w & 0xffff0000u);
                #pragma unroll
                for (int r = 0; r < RB; ++r) {
                    float d0 = sA[j][r];
                    d0 = fmaf(e0, xq[r][0].x, d0);
                    d0 = fmaf(e1, xq[r][0].y, d0);
                    d0 = fmaf(e2, xq[r][0].z, d0);
                    d0 = fmaf(e3, xq[r][0].w, d0);
                    d0 = fmaf(e4v, xq[r][1].x, d0);
                    d0 = fmaf(e5, xq[r][1].y, d0);
                    d0 = fmaf(e6, xq[r][1].z, d0);
                    d0 = fmaf(e7, xq[r][1].w, d0);
                    sA[j][r] = d0;
                }
            }
        }
        #pragma unroll
        for (int j = 0; j < 4; ++j) {
            float cs = esq[j * 256 + t];
            #pragma unroll
            for (int r = 0; r < RB; ++r)
                sA[j][r] = fmaf(-2.0f, sA[j][r], cs);
        }
        // per-row parallel min reduction
        #pragma unroll
        for (int r = 0; r < RB; ++r)
            minsh[r][t] = fminf(fminf(sA[0][r], sA[1][r]), fminf(sA[2][r], sA[3][r]));
        __syncthreads();
        for (int off = 128; off > 0; off >>= 1) {
            if (t < off) {
                #pragma unroll
                for (int r = 0; r < RB; ++r)
                    minsh[r][t] = fminf(minsh[r][t], minsh[r][t + off]);
            }
            __syncthreads();
        }
        if (t < RB) thrsh[t] = minsh[t][0] + SHORTLIST_EPS;
        __syncthreads();
        // shortlist build
        #pragma unroll
        for (int j = 0; j < 4; ++j)
            #pragma unroll
            for (int r = 0; r < RB; ++r)
                if (r < nr && sA[j][r] <= thrsh[r]) {
                    int p = atomicAdd(&scnt[r], 1);
                    if (p < 32) slist[r][p] = j * 256 + t;
                }
        __syncthreads();
        // phase B: thread -> (row r = t>>5, shortlist slot k = t&31)
        {
            int r = t >> 5, k = t & 31;
            int ns = scnt[r] < 32 ? scnt[r] : 32;
            if (r < nr && k < ns) {
                int c = slist[r][k];
                const float4* ec4 = (const float4*)(e + (size_t)c * DIM);
                const float4* xc4 = (const float4*)xsh[r];
                double dot = 0.0;
                #pragma unroll 8
                for (int d4 = 0; d4 < 64; ++d4) {
                    float4 ev = ec4[d4];
                    float4 xv = xc4[d4];
                    dot += (double)ev.x * (double)xv.x + (double)ev.y * (double)xv.y
                         + (double)ev.z * (double)xv.z + (double)ev.w * (double)xv.w;
                }
                float M = (float)dot;
                sres[r][k] = __fsub_rn(__fadd_rn(Ash[r], esq[c]), __fmul_rn(2.0f, M));
            }
        }
        __syncthreads();
        if (t < nr) {
            int ns = scnt[t] < 32 ? scnt[t] : 32;
            float bb = FLT_MAX; int ii = INT_MAX;
            for (int k = 0; k < ns; ++k) {
                float s = sres[t][k]; int c = slist[t][k];
                if (s < bb || (s == bb && c < ii)) { bb = s; ii = c; }
            }
            wsIdx[flagList[base + t]] = ii;
        }
    }
}

// ---------------- Kernel B: gather quantized + SSE partials + indices-as-float ----------------
__global__ void gather_kernel(const float* __restrict__ x, const float* __restrict__ e,
                              const int* __restrict__ wsIdx, float* __restrict__ out,
                              double* __restrict__ partials) {
    const float4* x4 = (const float4*)x;
    const float4* e4 = (const float4*)e;
    float4* q4 = (float4*)out;
    float* outIdx = out + OUT_IDX_OFF;
    const int tid = blockIdx.x * 256 + threadIdx.x;   // 0..262143
    double sse = 0.0;
    #pragma unroll 4
    for (int i = 0; i < 16; ++i) {
        int u = tid + i * 262144;      // float4 unit, 0..4194303
        int row = u >> 6;
        int c4 = u & 63;
        int idx = wsIdx[row];
        float4 q = e4[idx * 64 + c4];
        float4 xv = x4[u];
        q4[u] = q;
        double dx = (double)q.x - (double)xv.x;
        double dy = (double)q.y - (double)xv.y;
        double dz = (double)q.z - (double)xv.z;
        double dw = (double)q.w - (double)xv.w;
        sse += dx * dx + dy * dy + dz * dz + dw * dw;
    }
    if (tid < N_ROWS) outIdx[tid] = (float)wsIdx[tid];
    #pragma unroll
    for (int m = 1; m < 64; m <<= 1) sse += __shfl_xor(sse, m);
    __shared__ double wsum[4];
    if ((threadIdx.x & 63) == 0) wsum[threadIdx.x >> 6] = sse;
    __syncthreads();
    if (threadIdx.x == 0)
        partials[blockIdx.x] = wsum[0] + wsum[1] + wsum[2] + wsum[3];
}

// ---------------- Kernel C: final loss reduce ----------------
__global__ void loss_kernel(const double* __restrict__ partials, float* __restrict__ out) {
    __shared__ double sh[256];
    const int t = threadIdx.x;
    double s = partials[t] + partials[t + 256] + partials[t + 512] + partials[t + 768];
    sh[t] = s;
    __syncthreads();
    for (int off = 128; off > 0; off >>= 1) {
        if (t < off) sh[t] += sh[t + off];
        __syncthreads();
    }
    if (t == 0) out[OUT_LOSS_OFF] = (float)(0.25 * sh[0] / (double)N_ELEM);
}

extern "C" void kernel_launch(void* const* d_in, const int* in_sizes, int n_in,
                              void* d_out, int out_size, void* d_ws, size_t ws_size,
                              hipStream_t stream) {
    (void)in_sizes; (void)n_in; (void)out_size; (void)ws_size;
    const float* x = (const float*)d_in[0];
    const float* e = (const float*)d_in[1];
    float* out = (float*)d_out;
    char* ws = (char*)d_ws;
    double* partials = (double*)(ws + WS_PARTIALS);
    float* esq = (float*)(ws + WS_ESQ);
    int* wsIdx = (int*)(ws + WS_IDX);
    int* flagCnt = (int*)(ws + WS_FLAGCNT);
    int* flagList = (int*)(ws + WS_FLAGLIST);
    u16* ehi = (u16*)(ws + WS_EHI);
    u16* elo = (u16*)(ws + WS_ELO);
    u16* ehiT = (u16*)(ws + WS_EHIT);

    hipMemsetAsync(flagCnt, 0, sizeof(int), stream);
    esplit_kernel<<<256, 256, 0, stream>>>(e, ehi, elo, ehiT);
    esq_kernel<<<4, 256, 0, stream>>>(e, esq);
    argmin_kernel<<<N_ROWS / ROWS_PB, 512, 0, stream>>>(x, ehi, elo, esq,
                                                        wsIdx, flagCnt, flagList);
    rescore_kernel<<<512, 256, 0, stream>>>(x, e, ehiT, esq, wsIdx, flagCnt, flagList);
    gather_kernel<<<1024, 256, 0, stream>>>(x, e, wsIdx, out, partials);
    loss_kernel<<<1, 256, 0, stream>>>(partials, out);
}

// Round 6
// 299.846 us; speedup vs baseline: 1.2619x; 1.0461x over previous
//
#include <hip/hip_runtime.h>
#include <cfloat>
#include <climits>

// Problem constants
#define N_ROWS 65536          // 64*1024 flattened rows
#define DIM 256
#define K_CODES 1024
#define N_ELEM 16777216       // N_ROWS*DIM
#define OUT_LOSS_OFF 16777216
#define OUT_IDX_OFF  16777217

#define ROWS_PB 128           // rows per block (argmin)
#define CT 128                // codes per tile
// Ref computes dists in fp32 with +||x||^2 (~256) -> grid ulp ~3.05e-5; flips
// need exact gap <= ~6.5e-5. Pass-1 (bf16-split MFMA) error ~2e-6..4e-6. Margin
// 1.5e-4 keeps >18x safety. EPS logic needs only |err| << margin - any
// nearest-rounding split qualifies (R5-proven: cvt_pk RNE split, absmax 3.8e-6).
#define EPS_MARGIN 1.5e-4f
#define SHORTLIST_EPS 6e-4f   // covers exact-gap 6.6e-5 + 2*max|x.elo| ~4.2e-4
#define RB 8                  // flagged rows batched per rescore block

// ws layout (bytes)
#define WS_PARTIALS 0         // 1024 double
#define WS_ESQ      8192      // 1024 float
#define WS_IDX      12288     // 65536 int
#define WS_FLAGCNT  274432    // 1 int
#define WS_FLAGLIST 274436    // up to 65536 int -> ends 536580
#define WS_EHI      540672    // 1024*256 u16 = 512 KB (row-major, for argmin)
#define WS_ELO      1064960   // 512 KB
#define WS_EHIT     1589248   // 512 KB q-major transpose (for rescore) -> ends 2113536

typedef unsigned short u16;
typedef __attribute__((ext_vector_type(8))) short bf16x8;
typedef __attribute__((ext_vector_type(4))) float f32x4;
typedef union { bf16x8 v; unsigned u[4]; } frag_u;

// ---- async global->LDS 16B (wave-uniform LDS base + lane*16) ----
__device__ __forceinline__ void glds16(const void* g, void* l) {
    __builtin_amdgcn_global_load_lds(
        (const __attribute__((address_space(1))) unsigned int*)g,
        (__attribute__((address_space(3))) unsigned int*)l,
        16, 0, 0);
}

// ---- packed f32->bf16 RNE (2 elements/op); pure asm (no side effects) ----
__device__ __forceinline__ unsigned cvt_pk_bf16(float lo, float hi) {
    unsigned r;
    asm("v_cvt_pk_bf16_f32 %0, %1, %2" : "=v"(r) : "v"(lo), "v"(hi));
    return r;
}

// ---- exact two-term bf16 split of 8 f32 -> (hi8, lo8) fragments ----
// hi = RNE-bf16(x); lf = x - hi (exact, Sterbenz); lo = RNE-bf16(lf).
__device__ __forceinline__ void split8(float4 a, float4 b, bf16x8& h8, bf16x8& l8) {
    frag_u H, L;
    float f0 = a.x, f1 = a.y, f2 = a.z, f3 = a.w;
    float f4 = b.x, f5 = b.y, f6 = b.z, f7 = b.w;
    const float* f[8] = {&f0,&f1,&f2,&f3,&f4,&f5,&f6,&f7};
    #pragma unroll
    for (int p = 0; p < 4; ++p) {
        float xl = *f[2*p], xh = *f[2*p+1];
        unsigned hw = cvt_pk_bf16(xl, xh);
        float hfl = __uint_as_float(hw << 16);
        float hfh = __uint_as_float(hw & 0xffff0000u);
        H.u[p] = hw;
        L.u[p] = cvt_pk_bf16(xl - hfl, xh - hfh);
    }
    h8 = H.v; l8 = L.v;
}

// ---- exact two-term bf16 split (RN, scalar bit version - eprep only) ----
__device__ __forceinline__ void bsplit(float x, u16& h, u16& l) {
    unsigned u = __float_as_uint(x);
    unsigned hb = (u + 0x7fffu + ((u >> 16) & 1u)) >> 16;
    h = (u16)hb;
    float hf = __uint_as_float(hb << 16);
    float lf = x - hf;                       // exact
    unsigned u2 = __float_as_uint(lf);
    l = (u16)((u2 + 0x7fffu + ((u2 >> 16) & 1u)) >> 16);
}

// ---- numpy fp32 pairwise sum-of-squares over 256 elements (round-3 proven) ----
__device__ __forceinline__ float np_pairwise_sumsq(const float* __restrict__ a) {
    float half[2];
    #pragma unroll
    for (int h = 0; h < 2; ++h) {
        const float* p = a + h * 128;
        float r[8];
        #pragma unroll
        for (int j = 0; j < 8; ++j) r[j] = __fmul_rn(p[j], p[j]);
        for (int i = 8; i < 128; i += 8) {
            #pragma unroll
            for (int j = 0; j < 8; ++j)
                r[j] = __fadd_rn(r[j], __fmul_rn(p[i + j], p[i + j]));
        }
        half[h] = __fadd_rn(__fadd_rn(__fadd_rn(r[0], r[1]), __fadd_rn(r[2], r[3])),
                            __fadd_rn(__fadd_rn(r[4], r[5]), __fadd_rn(r[6], r[7])));
    }
    return __fadd_rn(half[0], half[1]);
}

// ---- fused e-prep: esplit (blocks 0..255) + esq (blocks 256..259) + flag zero ----
// Both paths are tiny (260 blocks total); fusing saves 2 dispatch boundaries
// (R5 accounting: ~145us of wall is boundary/tail overhead over 7 dispatches).
// ehiT layout: [qid 0..31][code 0..1023][8 u16], qid = 16B-chunk of the dim axis.
__launch_bounds__(256)
__global__ void eprep_kernel(const float* __restrict__ e, u16* __restrict__ ehi,
                             u16* __restrict__ elo, u16* __restrict__ ehiT,
                             float* __restrict__ esqOut, int* __restrict__ flagCnt) {
    const int b = blockIdx.x;
    if (b < 256) {
        int i4 = b * 256 + threadIdx.x;            // 0..65535
        float4 v = ((const float4*)e)[i4];
        ushort4 h, l;
        bsplit(v.x, h.x, l.x); bsplit(v.y, h.y, l.y);
        bsplit(v.z, h.z, l.z); bsplit(v.w, h.w, l.w);
        ((ushort4*)ehi)[i4] = h;
        ((ushort4*)elo)[i4] = l;
        int c = i4 >> 6;
        int f4 = i4 & 63;
        int qid = f4 >> 1;
        ((ushort4*)ehiT)[((size_t)qid * 1024 + c) * 2 + (f4 & 1)] = h;
    } else {
        if (b == 256 && threadIdx.x == 0) *flagCnt = 0;
        int c = (b - 256) * 256 + threadIdx.x;
        if (c < K_CODES) esqOut[c] = np_pairwise_sumsq(e + c * DIM);
    }
}

// ---------------- Kernel A: split-bf16 MFMA distance + argmin ----------------
// R1-proven schedule+compute (112us MFMA path): 8 waves (512 thr) in 4x2 over a
// 128x128 tile (wave = 32 rows x 64 codes); 66KB LDS -> 2 blocks/CU = 16
// waves/CU; cross-block overlap hides the serial stage->drain latency (R3:
// dbuf at 1 block/CU regressed to 180us - __syncthreads drains vmcnt(0)
// including just-issued prefetch; do not pipeline without counted-vmcnt raw
// barriers).
// R6: x is register-staged with an in-staging split (global f32 -> cvt_pk RNE
// bf16 hi/lo -> ds_write_b128 into the R1 LDS layout). This removes the xsplit
// kernel's 128MB HBM round-trip (R5 win) while taking the split VALU off the
// MFMA instruction stream (R5 regression: 96 VALU/chunk inside the kk loop,
// x8 redundant across ct). Each element is now split once per chunk by one
// thread; MFMA-wave code is byte-identical to R1.
// LDS tiles [128][64] u16; 16B-block slot jb holds source block jb^(row&7)
// (R1 swizzle). ds_write pattern: 8 lanes/pass cover all 32 banks (conflict-
// free); global reads permuted within 256B rows (line-granular coalescing OK).
__launch_bounds__(512, 4)
__global__ void argmin_kernel(const float* __restrict__ x,
                              const u16* __restrict__ ehi, const u16* __restrict__ elo,
                              const float* __restrict__ esq, int* __restrict__ wsIdx,
                              int* __restrict__ flagCnt, int* __restrict__ flagList) {
    __shared__ __align__(16) unsigned char lds[65536];
    __shared__ float esq_s[CT];
    u16* xhiS = (u16*)lds;              // [128][64] swizzled, 16 KB
    u16* xloS = (u16*)(lds + 16384);
    u16* ehiS = (u16*)(lds + 32768);
    u16* eloS = (u16*)(lds + 49152);

    const int t = threadIdx.x;
    const int w = t >> 6;               // wave 0..7
    const int l = t & 63;
    const int lane15 = l & 15;
    const int quad = l >> 4;            // 0..3
    const int rowBase = blockIdx.x * ROWS_PB;
    const int wr = w >> 1;              // 0..3: 32-row group
    const int wc = w & 1;               // 0..1: 64-code group

    float bv[8], sv[8]; int bi[8];
    #pragma unroll
    for (int i = 0; i < 8; ++i) { bv[i] = FLT_MAX; sv[i] = FLT_MAX; bi[i] = INT_MAX; }

    // e staging roles (glds16, unchanged from R5): waves 4,5 -> ehi halves,
    // waves 6,7 -> elo halves; 8 loads of 8 rows each.
    const int sub8 = l >> 3;            // e: row-in-group-of-8
    const int jb8 = l & 7;              // e: 16B-block slot in 128B row
    const int sb8 = jb8 ^ sub8;         // e: swizzled source block
    const u16* srcE = (w < 6) ? ehi : elo;
    u16* dstE = (w < 6) ? ehiS : eloS;
    const int halfE = w & 1;

    // x staging decomposition: 1024 groups of 8 floats per chunk; 2 per thread.
    // group g: row r=g>>3, dest slot jb=g&7, source block sb=jb^(r&7).
    const int g0 = t;                   // rows 0..63
    const int g1 = 512 + t;             // rows 64..127
    const int r0 = g0 >> 3, jb0 = g0 & 7, sb0 = jb0 ^ (r0 & 7);
    const int r1 = g1 >> 3, jb1 = g1 & 7, sb1 = jb1 ^ (r1 & 7);

    for (int ct = 0; ct < 8; ++ct) {
        const int ctBase = ct * CT;
        __syncthreads();                          // prior epilogue/LDS reads done
        if (t < CT) esq_s[t] = esq[ctBase + t];

        f32x4 acc[2][4];
        #pragma unroll
        for (int ti = 0; ti < 2; ++ti)
            #pragma unroll
            for (int tj = 0; tj < 4; ++tj) acc[ti][tj] = (f32x4){0.f, 0.f, 0.f, 0.f};

        for (int ch = 0; ch < 4; ++ch) {
            __syncthreads();
            // issue x register loads first (waits on these only), then e DMA
            const float4* gp0 = (const float4*)(x + (size_t)(rowBase + r0) * 256 + ch * 64 + sb0 * 8);
            const float4* gp1 = (const float4*)(x + (size_t)(rowBase + r1) * 256 + ch * 64 + sb1 * 8);
            float4 va0 = gp0[0], vb0 = gp0[1];
            float4 va1 = gp1[0], vb1 = gp1[1];
            if (w >= 4) {
                #pragma unroll
                for (int i = 0; i < 8; ++i) {
                    int r = halfE * 64 + i * 8 + sub8;
                    glds16(srcE + (size_t)(ctBase + r) * 256 + ch * 64 + sb8 * 8,
                           dstE + halfE * 4096 + i * 512);
                }
            }
            {
                bf16x8 h8, l8;
                split8(va0, vb0, h8, l8);
                *(bf16x8*)(xhiS + r0 * 64 + jb0 * 8) = h8;
                *(bf16x8*)(xloS + r0 * 64 + jb0 * 8) = l8;
                split8(va1, vb1, h8, l8);
                *(bf16x8*)(xhiS + r1 * 64 + jb1 * 8) = h8;
                *(bf16x8*)(xloS + r1 * 64 + jb1 * 8) = l8;
            }
            __syncthreads();

            #pragma unroll
            for (int kk = 0; kk < 2; ++kk) {      // two 32-wide k-steps
                bf16x8 ah[2], al4[2], bh[4], bl[4];
                const int blk = kk * 4 + quad;    // 16B-block index in row
                #pragma unroll
                for (int ti = 0; ti < 2; ++ti) {
                    int r = wr * 32 + ti * 16 + lane15;
                    int off = r * 64 + ((blk ^ (r & 7)) * 8);
                    ah[ti]  = *(const bf16x8*)(xhiS + off);
                    al4[ti] = *(const bf16x8*)(xloS + off);
                }
                #pragma unroll
                for (int tj = 0; tj < 4; ++tj) {
                    int r = wc * 64 + tj * 16 + lane15;
                    int off = r * 64 + ((blk ^ (r & 7)) * 8);
                    bh[tj] = *(const bf16x8*)(ehiS + off);
                    bl[tj] = *(const bf16x8*)(eloS + off);
                }
                #pragma unroll
                for (int ti = 0; ti < 2; ++ti)
                    #pragma unroll
                    for (int tj = 0; tj < 4; ++tj) {
                        acc[ti][tj] = __builtin_amdgcn_mfma_f32_16x16x32_bf16(al4[ti], bh[tj], acc[ti][tj], 0, 0, 0);
                        acc[ti][tj] = __builtin_amdgcn_mfma_f32_16x16x32_bf16(ah[ti], bl[tj], acc[ti][tj], 0, 0, 0);
                        acc[ti][tj] = __builtin_amdgcn_mfma_f32_16x16x32_bf16(ah[ti], bh[tj], acc[ti][tj], 0, 0, 0);
                    }
            }
        }

        // epilogue: s = ||e||^2 - 2*dot. D-layout: row(M)=quad*4+reg, col(N)=lane&15.
        #pragma unroll
        for (int tj = 0; tj < 4; ++tj) {
            int cLoc = wc * 64 + tj * 16 + lane15;
            float cs = esq_s[cLoc];
            int c = ctBase + cLoc;
            #pragma unroll
            for (int ti = 0; ti < 2; ++ti)
                #pragma unroll
                for (int r4 = 0; r4 < 4; ++r4) {
                    int slot = ti * 4 + r4;
                    float s = fmaf(-2.0f, acc[ti][tj][r4], cs);
                    if (s < bv[slot]) {           // candidates ascend in c
                        sv[slot] = bv[slot]; bv[slot] = s; bi[slot] = c;
                    } else if (s < sv[slot]) {
                        sv[slot] = s;
                    }
                }
        }
    }

    // ---- final cross-contributor top-2 merge via LDS (reuses tile memory) ----
    // stride 33 floats: bank = (row+k)%32 -> conflict-free (round-6 proven).
    __syncthreads();
    float* bvA = (float*)lds;                     // [128 rows][33]
    float* svA = (float*)(lds + 16896);
    int*   biA = (int*)(lds + 33792);
    const int contrib = wc * 16 + lane15;         // 0..31
    #pragma unroll
    for (int slot = 0; slot < 8; ++slot) {
        int m = wr * 32 + (slot >> 2) * 16 + quad * 4 + (slot & 3);
        bvA[m * 33 + contrib] = bv[slot];
        svA[m * 33 + contrib] = sv[slot];
        biA[m * 33 + contrib] = bi[slot];
    }
    __syncthreads();

    if (t < ROWS_PB) {
        float bb = FLT_MAX, ss = FLT_MAX;
        int ii = INT_MAX;
        for (int k = 0; k < 32; ++k) {
            float v  = bvA[t * 33 + k];
            int   id = biA[t * 33 + k];
            float s2 = svA[t * 33 + k];
            if (v < bb || (v == bb && id < ii)) {
                ss = fminf(bb, s2);
                bb = v; ii = id;
            } else {
                ss = fminf(ss, v);
            }
        }
        int row = rowBase + t;
        wsIdx[row] = ii;
        if (ss - bb < EPS_MARGIN) {
            int p = atomicAdd(flagCnt, 1);
            flagList[p] = row;
        }
    }
}

// ------- Kernel A2: flagged-row rescore, RB rows batched per block -------
// Phase A: bf16-hi fp32 scores over all 1024 codes via q-major ehiT
// (coalesced; each ehi byte read once per 8 rows) -> per-row shortlist within
// SHORTLIST_EPS of min. Phase B: numpy-emulated quantized score (round-3/4
// proven formula) on shortlist; lexicographic (s, idx) argmin.
__launch_bounds__(256)
__global__ void rescore_kernel(const float* __restrict__ x, const float* __restrict__ e,
                               const u16* __restrict__ ehiT, const float* __restrict__ esq,
                               int* __restrict__ wsIdx, const int* __restrict__ flagCnt,
                               const int* __restrict__ flagList) {
    __shared__ __align__(16) float xsh[RB][DIM];      // 8 KB
    __shared__ float Ash[RB];
    __shared__ float minsh[RB][256];                  // 8 KB
    __shared__ float thrsh[RB];
    __shared__ int scnt[RB];
    __shared__ int slist[RB][32];
    __shared__ float sres[RB][32];
    const int t = threadIdx.x;
    const int cnt = *flagCnt;
    const int ngroups = (cnt + RB - 1) / RB;
    for (int g = blockIdx.x; g < ngroups; g += gridDim.x) {
        const int base = g * RB;
        const int nr = (cnt - base < RB) ? (cnt - base) : RB;
        __syncthreads();                               // protect reuse across groups
        #pragma unroll
        for (int r = 0; r < RB; ++r)
            xsh[r][t] = (r < nr) ? x[(size_t)flagList[base + r] * DIM + t] : 0.0f;
        if (t < RB) scnt[t] = 0;
        __syncthreads();
        if (t < RB) Ash[t] = np_pairwise_sumsq(xsh[t]);

        // phase A: sA[j][r] = dot(x_r, ehi_c), c = j*256+t
        float sA[4][RB];
        #pragma unroll
        for (int j = 0; j < 4; ++j)
            #pragma unroll
            for (int r = 0; r < RB; ++r) sA[j][r] = 0.0f;

        const uint4* eT4 = (const uint4*)ehiT;
        for (int q = 0; q < 32; ++q) {
            float4 xq[RB][2];
            #pragma unroll
            for (int r = 0; r < RB; ++r) {             // broadcast LDS reads
                xq[r][0] = ((const float4*)xsh[r])[2 * q];
                xq[r][1] = ((const float4*)xsh[r])[2 * q + 1];
            }
            #pragma unroll
            for (int j = 0; j < 4; ++j) {
                uint4 uv = eT4[(size_t)q * 1024 + j * 256 + t];   // coalesced
                float e0 = __uint_as_float(uv.x << 16);
                float e1 = __uint_as_float(uv.x & 0xffff0000u);
                float e2 = __uint_as_float(uv.y << 16);
                float e3 = __uint_as_float(uv.y & 0xffff0000u);
                float e4v = __uint_as_float(uv.z << 16);
                float e5 = __uint_as_float(uv.z & 0xffff0000u);
                float e6 = __uint_as_float(uv.w << 16);
                float e7 = __uint_as_float(uv.w & 0xffff0000u);
                #pragma unroll
                for (int r = 0; r < RB; ++r) {
                    float d0 = sA[j][r];
                    d0 = fmaf(e0, xq[r][0].x, d0);
                    d0 = fmaf(e1, xq[r][0].y, d0);
                    d0 = fmaf(e2, xq[r][0].z, d0);
                    d0 = fmaf(e3, xq[r][0].w, d0);
                    d0 = fmaf(e4v, xq[r][1].x, d0);
                    d0 = fmaf(e5, xq[r][1].y, d0);
                    d0 = fmaf(e6, xq[r][1].z, d0);
                    d0 = fmaf(e7, xq[r][1].w, d0);
                    sA[j][r] = d0;
                }
            }
        }
        #pragma unroll
        for (int j = 0; j < 4; ++j) {
            float cs = esq[j * 256 + t];
            #pragma unroll
            for (int r = 0; r < RB; ++r)
                sA[j][r] = fmaf(-2.0f, sA[j][r], cs);
        }
        // per-row parallel min reduction
        #pragma unroll
        for (int r = 0; r < RB; ++r)
            minsh[r][t] = fminf(fminf(sA[0][r], sA[1][r]), fminf(sA[2][r], sA[3][r]));
        __syncthreads();
        for (int off = 128; off > 0; off >>= 1) {
            if (t < off) {
                #pragma unroll
                for (int r = 0; r < RB; ++r)
                    minsh[r][t] = fminf(minsh[r][t], minsh[r][t + off]);
            }
            __syncthreads();
        }
        if (t < RB) thrsh[t] = minsh[t][0] + SHORTLIST_EPS;
        __syncthreads();
        // shortlist build
        #pragma unroll
        for (int j = 0; j < 4; ++j)
            #pragma unroll
            for (int r = 0; r < RB; ++r)
                if (r < nr && sA[j][r] <= thrsh[r]) {
                    int p = atomicAdd(&scnt[r], 1);
                    if (p < 32) slist[r][p] = j * 256 + t;
                }
        __syncthreads();
        // phase B: thread -> (row r = t>>5, shortlist slot k = t&31)
        {
            int r = t >> 5, k = t & 31;
            int ns = scnt[r] < 32 ? scnt[r] : 32;
            if (r < nr && k < ns) {
                int c = slist[r][k];
                const float4* ec4 = (const float4*)(e + (size_t)c * DIM);
                const float4* xc4 = (const float4*)xsh[r];
                double dot = 0.0;
                #pragma unroll 8
                for (int d4 = 0; d4 < 64; ++d4) {
                    float4 ev = ec4[d4];
                    float4 xv = xc4[d4];
                    dot += (double)ev.x * (double)xv.x + (double)ev.y * (double)xv.y
                         + (double)ev.z * (double)xv.z + (double)ev.w * (double)xv.w;
                }
                float M = (float)dot;
                sres[r][k] = __fsub_rn(__fadd_rn(Ash[r], esq[c]), __fmul_rn(2.0f, M));
            }
        }
        __syncthreads();
        if (t < nr) {
            int ns = scnt[t] < 32 ? scnt[t] : 32;
            float bb = FLT_MAX; int ii = INT_MAX;
            for (int k = 0; k < ns; ++k) {
                float s = sres[t][k]; int c = slist[t][k];
                if (s < bb || (s == bb && c < ii)) { bb = s; ii = c; }
            }
            wsIdx[flagList[base + t]] = ii;
        }
    }
}

// ---------------- Kernel B: gather quantized + SSE partials + indices-as-float ----------------
__global__ void gather_kernel(const float* __restrict__ x, const float* __restrict__ e,
                              const int* __restrict__ wsIdx, float* __restrict__ out,
                              double* __restrict__ partials) {
    const float4* x4 = (const float4*)x;
    const float4* e4 = (const float4*)e;
    float4* q4 = (float4*)out;
    float* outIdx = out + OUT_IDX_OFF;
    const int tid = blockIdx.x * 256 + threadIdx.x;   // 0..262143
    double sse = 0.0;
    #pragma unroll 4
    for (int i = 0; i < 16; ++i) {
        int u = tid + i * 262144;      // float4 unit, 0..4194303
        int row = u >> 6;
        int c4 = u & 63;
        int idx = wsIdx[row];
        float4 q = e4[idx * 64 + c4];
        float4 xv = x4[u];
        q4[u] = q;
        double dx = (double)q.x - (double)xv.x;
        double dy = (double)q.y - (double)xv.y;
        double dz = (double)q.z - (double)xv.z;
        double dw = (double)q.w - (double)xv.w;
        sse += dx * dx + dy * dy + dz * dz + dw * dw;
    }
    if (tid < N_ROWS) outIdx[tid] = (float)wsIdx[tid];
    #pragma unroll
    for (int m = 1; m < 64; m <<= 1) sse += __shfl_xor(sse, m);
    __shared__ double wsum[4];
    if ((threadIdx.x & 63) == 0) wsum[threadIdx.x >> 6] = sse;
    __syncthreads();
    if (threadIdx.x == 0)
        partials[blockIdx.x] = wsum[0] + wsum[1] + wsum[2] + wsum[3];
}

// ---------------- Kernel C: final loss reduce ----------------
__global__ void loss_kernel(const double* __restrict__ partials, float* __restrict__ out) {
    __shared__ double sh[256];
    const int t = threadIdx.x;
    double s = partials[t] + partials[t + 256] + partials[t + 512] + partials[t + 768];
    sh[t] = s;
    __syncthreads();
    for (int off = 128; off > 0; off >>= 1) {
        if (t < off) sh[t] += sh[t + off];
        __syncthreads();
    }
    if (t == 0) out[OUT_LOSS_OFF] = (float)(0.25 * sh[0] / (double)N_ELEM);
}

extern "C" void kernel_launch(void* const* d_in, const int* in_sizes, int n_in,
                              void* d_out, int out_size, void* d_ws, size_t ws_size,
                              hipStream_t stream) {
    (void)in_sizes; (void)n_in; (void)out_size; (void)ws_size;
    const float* x = (const float*)d_in[0];
    const float* e = (const float*)d_in[1];
    float* out = (float*)d_out;
    char* ws = (char*)d_ws;
    double* partials = (double*)(ws + WS_PARTIALS);
    float* esq = (float*)(ws + WS_ESQ);
    int* wsIdx = (int*)(ws + WS_IDX);
    int* flagCnt = (int*)(ws + WS_FLAGCNT);
    int* flagList = (int*)(ws + WS_FLAGLIST);
    u16* ehi = (u16*)(ws + WS_EHI);
    u16* elo = (u16*)(ws + WS_ELO);
    u16* ehiT = (u16*)(ws + WS_EHIT);

    eprep_kernel<<<260, 256, 0, stream>>>(e, ehi, elo, ehiT, esq, flagCnt);
    argmin_kernel<<<N_ROWS / ROWS_PB, 512, 0, stream>>>(x, ehi, elo, esq,
                                                        wsIdx, flagCnt, flagList);
    rescore_kernel<<<512, 256, 0, stream>>>(x, e, ehiT, esq, wsIdx, flagCnt, flagList);
    gather_kernel<<<1024, 256, 0, stream>>>(x, e, wsIdx, out, partials);
    loss_kernel<<<1, 256, 0, stream>>>(partials, out);
}